// Round 1
// baseline (1312.700 us; speedup 1.0000x reference)
//
#include <hip/hip_runtime.h>
#include <math.h>

#define KNN 20
#define NS 0.2f
#define EPSV 1e-6f
#define QT 4
#define OT 8

// ---------------- transpose (B,N,3) -> (B,3,N) ----------------
__global__ void k_transpose(const float* __restrict__ x, float* __restrict__ xt,
                            int B, int N) {
    int i = blockIdx.x * blockDim.x + threadIdx.x;
    if (i >= B * N) return;
    int b = i / N, n = i % N;
    const float* src = x + (size_t)(b * N + n) * 3;
    float* dst = xt + (size_t)b * 3 * N + n;
    dst[0] = src[0];
    dst[(size_t)N] = src[1];
    dst[(size_t)2 * N] = src[2];
}

// ---------------- squared norms xx[b,n] = sum_d X[b,d,n]^2 ----------------
__global__ void k_sqnorm(const float* __restrict__ X, float* __restrict__ xx,
                         int B, int N, int D, long batchStride, long sliceOff) {
    int i = blockIdx.x * blockDim.x + threadIdx.x;
    if (i >= B * N) return;
    int b = i / N, n = i % N;
    const float* p = X + (size_t)b * batchStride + sliceOff + n;
    float s = 0.f;
    for (int d = 0; d < D; ++d) {
        float v = p[(size_t)d * N];
        s += v * v;
    }
    xx[i] = s;
}

// ---------------- knn: block handles QT queries, N=1024, 256 threads ----------------
__global__ void k_knn(const float* __restrict__ X, const float* __restrict__ xx,
                      int* __restrict__ idx, int N, int D,
                      long batchStride, long sliceOff) {
    int b = blockIdx.y;
    int q0 = blockIdx.x * QT;
    int tid = threadIdx.x;

    __shared__ float qf[QT][128];     // D <= 126
    __shared__ float pd[QT][1024];    // N == 1024
    __shared__ float sv[256];
    __shared__ int si[256];

    const float* Xb = X + (size_t)b * batchStride + sliceOff;

    for (int t = tid; t < QT * D; t += 256) {
        int q = t / D, d = t % D;
        qf[q][d] = Xb[(size_t)d * N + (q0 + q)];
    }
    __syncthreads();

    float acc[QT * 4];
#pragma unroll
    for (int t = 0; t < QT * 4; ++t) acc[t] = 0.f;

    for (int d = 0; d < D; ++d) {
        const float* row = Xb + (size_t)d * N;
        float x0 = row[tid], x1 = row[tid + 256], x2 = row[tid + 512], x3 = row[tid + 768];
#pragma unroll
        for (int q = 0; q < QT; ++q) {
            float qv = qf[q][d];
            acc[q * 4 + 0] += qv * x0;
            acc[q * 4 + 1] += qv * x1;
            acc[q * 4 + 2] += qv * x2;
            acc[q * 4 + 3] += qv * x3;
        }
    }

#pragma unroll
    for (int q = 0; q < QT; ++q) {
        float xn = xx[b * N + q0 + q];
#pragma unroll
        for (int c = 0; c < 4; ++c) {
            int m = tid + 256 * c;
            pd[q][m] = 2.f * acc[q * 4 + c] - xn - xx[b * N + m];
        }
    }
    __syncthreads();

    for (int q = 0; q < QT; ++q) {
        long outBase = ((long)b * N + q0 + q) * KNN;
        for (int it = 0; it < KNN; ++it) {
            float bv = -INFINITY;
            int bi = N;
#pragma unroll
            for (int c = 0; c < 4; ++c) {
                int m = tid + 256 * c;
                float v = pd[q][m];
                if (v > bv || (v == bv && m < bi)) { bv = v; bi = m; }
            }
            sv[tid] = bv;
            si[tid] = bi;
            __syncthreads();
            for (int s = 128; s > 0; s >>= 1) {
                if (tid < s) {
                    float ov = sv[tid + s];
                    int oi = si[tid + s];
                    if (ov > sv[tid] || (ov == sv[tid] && oi < si[tid])) {
                        sv[tid] = ov; si[tid] = oi;
                    }
                }
                __syncthreads();
            }
            if (tid == 0) {
                idx[outBase + it] = si[0];
                pd[q][si[0]] = -INFINITY;
            }
            __syncthreads();
        }
    }
}

// ---------------- pair matmul: U = WA*x, V = (WB-WA)*x  (edge-factorized) ----------------
// W row-major (Cout, 2C): WA[o,c]=W[o,2C.. +c], WB[o,c]=W[..C+c]
__global__ void k_matmul_pair(const float* __restrict__ X, const float* __restrict__ W,
                              float* __restrict__ U, float* __restrict__ V,
                              int N, int C, int Cout, long batchStride, long sliceOff) {
    int j = blockIdx.y % 3;
    int ot = blockIdx.y / 3;
    int b = blockIdx.z;
    int o0 = ot * OT;
    int tid = threadIdx.x;
    int n = blockIdx.x * 256 + tid;

    __shared__ float wa[OT][64], wb[OT][64];   // C <= 42
    for (int t = tid; t < OT * C; t += 256) {
        int oo = t / C, c = t % C;
        int o = o0 + oo;
        float a = 0.f, bb = 0.f;
        if (o < Cout) {
            a = W[(size_t)o * 2 * C + c];
            bb = W[(size_t)o * 2 * C + C + c] - a;
        }
        wa[oo][c] = a;
        wb[oo][c] = bb;
    }
    __syncthreads();

    const float* Xp = X + (size_t)b * batchStride + sliceOff + (size_t)j * N + n;
    float au[OT], av[OT];
#pragma unroll
    for (int oo = 0; oo < OT; ++oo) { au[oo] = 0.f; av[oo] = 0.f; }

    for (int c = 0; c < C; ++c) {
        float xv = Xp[(size_t)c * 3 * N];
#pragma unroll
        for (int oo = 0; oo < OT; ++oo) {
            au[oo] += wa[oo][c] * xv;
            av[oo] += wb[oo][c] * xv;
        }
    }
#pragma unroll
    for (int oo = 0; oo < OT; ++oo) {
        int o = o0 + oo;
        if (o < Cout) {
            size_t off = (((size_t)b * Cout + o) * 3 + j) * N + n;
            U[off] = au[oo];
            V[off] = av[oo];
        }
    }
}

// ---------------- plain matmul (layer 5): U = W*x ----------------
__global__ void k_matmul_plain(const float* __restrict__ X, const float* __restrict__ W,
                               float* __restrict__ U,
                               int N, int Cin, int Cout, long batchStride, long sliceOff) {
    int j = blockIdx.y % 3;
    int ot = blockIdx.y / 3;
    int b = blockIdx.z;
    int o0 = ot * OT;
    int tid = threadIdx.x;
    int n = blockIdx.x * 256 + tid;

    __shared__ float wsm[OT][176];  // Cin <= 169
    for (int t = tid; t < OT * Cin; t += 256) {
        int oo = t / Cin, c = t % Cin;
        int o = o0 + oo;
        wsm[oo][c] = (o < Cout) ? W[(size_t)o * Cin + c] : 0.f;
    }
    __syncthreads();

    const float* Xp = X + (size_t)b * batchStride + sliceOff + (size_t)j * N + n;
    float au[OT];
#pragma unroll
    for (int oo = 0; oo < OT; ++oo) au[oo] = 0.f;

    for (int c = 0; c < Cin; ++c) {
        float xv = Xp[(size_t)c * 3 * N];
#pragma unroll
        for (int oo = 0; oo < OT; ++oo) au[oo] += wsm[oo][c] * xv;
    }
#pragma unroll
    for (int oo = 0; oo < OT; ++oo) {
        int o = o0 + oo;
        if (o < Cout) U[(((size_t)b * Cout + o) * 3 + j) * N + n] = au[oo];
    }
}

// ---------------- BN stats over edges: sums[2o]=Σ||p||, sums[2o+1]=Σ||p||² ----------------
__global__ void k_stats_edge(const float* __restrict__ U, const float* __restrict__ V,
                             const int* __restrict__ idx, float* __restrict__ sums,
                             int N, int Cout) {
    int b = blockIdx.z, o = blockIdx.y, tid = threadIdx.x;
    int n = blockIdx.x * 256 + tid;
    const float* Ub = U + (((size_t)b * Cout + o) * 3) * N;
    const float* Vb = V + (((size_t)b * Cout + o) * 3) * N;
    float v0 = Vb[n], v1 = Vb[(size_t)N + n], v2 = Vb[(size_t)2 * N + n];
    const int* ip = idx + ((size_t)b * N + n) * KNN;
    float s = 0.f, s2 = 0.f;
    for (int kk = 0; kk < KNN; ++kk) {
        int m = ip[kk];
        float p0 = Ub[m] + v0;
        float p1 = Ub[(size_t)N + m] + v1;
        float p2 = Ub[(size_t)2 * N + m] + v2;
        float nm = sqrtf(p0 * p0 + p1 * p1 + p2 * p2) + EPSV;
        s += nm;
        s2 += nm * nm;
    }
    __shared__ float r1[256], r2[256];
    r1[tid] = s; r2[tid] = s2;
    __syncthreads();
    for (int st = 128; st > 0; st >>= 1) {
        if (tid < st) { r1[tid] += r1[tid + st]; r2[tid] += r2[tid + st]; }
        __syncthreads();
    }
    if (tid == 0) {
        atomicAdd(&sums[2 * o], r1[0]);
        atomicAdd(&sums[2 * o + 1], r2[0]);
    }
}

// ---------------- BN + dir leaky + mean-pool over k -> out slice ----------------
__global__ void k_final_edge(const float* __restrict__ U, const float* __restrict__ V,
                             const float* __restrict__ UD, const float* __restrict__ VD,
                             const int* __restrict__ idx, const float* __restrict__ sums,
                             const float* __restrict__ gamma, const float* __restrict__ beta,
                             float* __restrict__ out,
                             int N, int Cout, int outCtot, int outCoff, float cnt) {
    int b = blockIdx.z, o = blockIdx.y, tid = threadIdx.x;
    int n = blockIdx.x * 256 + tid;
    float mu = sums[2 * o] / cnt;
    float var = sums[2 * o + 1] / cnt - mu * mu;
    float inv = rsqrtf(var + 1e-5f);
    float g = gamma[o], bt = beta[o];

    const float* Ub = U + (((size_t)b * Cout + o) * 3) * N;
    const float* Vb = V + (((size_t)b * Cout + o) * 3) * N;
    const float* UDb = UD + (((size_t)b * Cout + o) * 3) * N;
    const float* VDb = VD + (((size_t)b * Cout + o) * 3) * N;

    float v0 = Vb[n], v1 = Vb[(size_t)N + n], v2 = Vb[(size_t)2 * N + n];
    float w0 = VDb[n], w1 = VDb[(size_t)N + n], w2 = VDb[(size_t)2 * N + n];
    const int* ip = idx + ((size_t)b * N + n) * KNN;

    float a0 = 0.f, a1 = 0.f, a2 = 0.f;
    for (int kk = 0; kk < KNN; ++kk) {
        int m = ip[kk];
        float p0 = Ub[m] + v0;
        float p1 = Ub[(size_t)N + m] + v1;
        float p2 = Ub[(size_t)2 * N + m] + v2;
        float nm = sqrtf(p0 * p0 + p1 * p1 + p2 * p2) + EPSV;
        float nbn = (nm - mu) * inv * g + bt;
        float sc = nbn / nm;
        p0 *= sc; p1 *= sc; p2 *= sc;
        float d0 = UDb[m] + w0;
        float d1 = UDb[(size_t)N + m] + w1;
        float d2 = UDb[(size_t)2 * N + m] + w2;
        float dot = p0 * d0 + p1 * d1 + p2 * d2;
        if (dot >= 0.f) {
            a0 += p0; a1 += p1; a2 += p2;
        } else {
            float f = dot / (d0 * d0 + d1 * d1 + d2 * d2 + EPSV);
            a0 += NS * p0 + (1.f - NS) * (p0 - f * d0);
            a1 += NS * p1 + (1.f - NS) * (p1 - f * d1);
            a2 += NS * p2 + (1.f - NS) * (p2 - f * d2);
        }
    }
    const float invk = 1.f / (float)KNN;
    size_t ob = (((size_t)b * outCtot + outCoff + o) * 3) * N + n;
    out[ob] = a0 * invk;
    out[ob + (size_t)N] = a1 * invk;
    out[ob + (size_t)2 * N] = a2 * invk;
}

// ---------------- layer-5 stats (no k) ----------------
__global__ void k_stats_plain(const float* __restrict__ U, float* __restrict__ sums,
                              int N, int Cout) {
    int b = blockIdx.z, o = blockIdx.y, tid = threadIdx.x;
    int n = blockIdx.x * 256 + tid;
    const float* Ub = U + (((size_t)b * Cout + o) * 3) * N;
    float p0 = Ub[n], p1 = Ub[(size_t)N + n], p2 = Ub[(size_t)2 * N + n];
    float nm = sqrtf(p0 * p0 + p1 * p1 + p2 * p2) + EPSV;
    __shared__ float r1[256], r2[256];
    r1[tid] = nm; r2[tid] = nm * nm;
    __syncthreads();
    for (int st = 128; st > 0; st >>= 1) {
        if (tid < st) { r1[tid] += r1[tid + st]; r2[tid] += r2[tid + st]; }
        __syncthreads();
    }
    if (tid == 0) {
        atomicAdd(&sums[2 * o], r1[0]);
        atomicAdd(&sums[2 * o + 1], r2[0]);
    }
}

// ---------------- layer-5 final: BN + dir leaky (1 dir channel) -> d_out ----------------
__global__ void k_final_plain(const float* __restrict__ U, const float* __restrict__ Dv,
                              const float* __restrict__ sums,
                              const float* __restrict__ gamma, const float* __restrict__ beta,
                              float* __restrict__ out, int N, int Cout, float cnt) {
    int b = blockIdx.z, o = blockIdx.y, tid = threadIdx.x;
    int n = blockIdx.x * 256 + tid;
    float mu = sums[2 * o] / cnt;
    float var = sums[2 * o + 1] / cnt - mu * mu;
    float inv = rsqrtf(var + 1e-5f);
    float g = gamma[o], bt = beta[o];

    const float* Ub = U + (((size_t)b * Cout + o) * 3) * N;
    float p0 = Ub[n], p1 = Ub[(size_t)N + n], p2 = Ub[(size_t)2 * N + n];
    float nm = sqrtf(p0 * p0 + p1 * p1 + p2 * p2) + EPSV;
    float nbn = (nm - mu) * inv * g + bt;
    float sc = nbn / nm;
    p0 *= sc; p1 *= sc; p2 *= sc;

    float d0 = Dv[((size_t)b * 3 + 0) * N + n];
    float d1 = Dv[((size_t)b * 3 + 1) * N + n];
    float d2 = Dv[((size_t)b * 3 + 2) * N + n];
    float dot = p0 * d0 + p1 * d1 + p2 * d2;
    float o0, o1, o2;
    if (dot >= 0.f) {
        o0 = p0; o1 = p1; o2 = p2;
    } else {
        float f = dot / (d0 * d0 + d1 * d1 + d2 * d2 + EPSV);
        o0 = NS * p0 + (1.f - NS) * (p0 - f * d0);
        o1 = NS * p1 + (1.f - NS) * (p1 - f * d1);
        o2 = NS * p2 + (1.f - NS) * (p2 - f * d2);
    }
    size_t ob = (((size_t)b * Cout + o) * 3) * N + n;
    out[ob] = o0;
    out[ob + (size_t)N] = o1;
    out[ob + (size_t)2 * N] = o2;
}

extern "C" void kernel_launch(void* const* d_in, const int* in_sizes, int n_in,
                              void* d_out, int out_size, void* d_ws, size_t ws_size,
                              hipStream_t stream) {
    (void)in_sizes; (void)n_in; (void)out_size; (void)ws_size;
    const int B = 8, N = 1024, CTOT = 169;

    const float* x = (const float*)d_in[0];
    const float* W[5]; const float* Dw[5]; const float* G[5]; const float* Bt[5];
    for (int l = 0; l < 5; ++l) {
        W[l]  = (const float*)d_in[1 + 4 * l];
        Dw[l] = (const float*)d_in[2 + 4 * l];
        G[l]  = (const float*)d_in[3 + 4 * l];
        Bt[l] = (const float*)d_in[4 + 4 * l];
    }

    float* ws = (float*)d_ws;
    size_t off = 0;
    float* xt = ws + off;    off += (size_t)B * 3 * N;
    float* xx = ws + off;    off += (size_t)B * N;
    int* idx = (int*)(ws + off); off += (size_t)B * N * KNN;
    float* cat = ws + off;   off += (size_t)B * CTOT * 3 * N;
    float* bufU = ws + off;  off += (size_t)B * 341 * 3 * N;
    float* bufV = ws + off;  off += (size_t)B * 85 * 3 * N;
    float* bufUD = ws + off; off += (size_t)B * 85 * 3 * N;
    float* bufVD = ws + off; off += (size_t)B * 85 * 3 * N;
    float* d5buf = ws + off; off += (size_t)B * 3 * N;
    float* stats = ws + off; off += 5 * 682;

    hipMemsetAsync(stats, 0, 5 * 682 * sizeof(float), stream);

    k_transpose<<<(B * N + 255) / 256, 256, 0, stream>>>(x, xt, B, N);

    // layers 1-4: {C_in, C_out, inCoff (into cat; -1 => xt), outCoff}
    const int Cin_[4]  = {1, 21, 21, 42};
    const int Cout_[4] = {21, 21, 42, 85};
    const int inOff_[4] = {-1, 0, 21, 42};
    const int outOff_[4] = {0, 21, 42, 84};

    for (int l = 0; l < 4; ++l) {
        int C = Cin_[l], Co = Cout_[l];
        const float* Xin;
        long bs, so;
        if (inOff_[l] < 0) { Xin = xt; bs = (long)3 * N; so = 0; }
        else { Xin = cat; bs = (long)CTOT * 3 * N; so = (long)inOff_[l] * 3 * N; }
        int D = C * 3;

        k_sqnorm<<<(B * N + 255) / 256, 256, 0, stream>>>(Xin, xx, B, N, D, bs, so);

        dim3 gk(N / QT, B);
        k_knn<<<gk, 256, 0, stream>>>(Xin, xx, idx, N, D, bs, so);

        dim3 gm(N / 256, 3 * ((Co + OT - 1) / OT), B);
        k_matmul_pair<<<gm, 256, 0, stream>>>(Xin, W[l], bufU, bufV, N, C, Co, bs, so);
        k_matmul_pair<<<gm, 256, 0, stream>>>(Xin, Dw[l], bufUD, bufVD, N, C, Co, bs, so);

        dim3 gs(N / 256, Co, B);
        k_stats_edge<<<gs, 256, 0, stream>>>(bufU, bufV, idx, stats + l * 682, N, Co);
        k_final_edge<<<gs, 256, 0, stream>>>(bufU, bufV, bufUD, bufVD, idx,
                                             stats + l * 682, G[l], Bt[l], cat,
                                             N, Co, CTOT, outOff_[l],
                                             (float)((size_t)B * N * KNN));
    }

    // layer 5 (no graph feature)
    {
        long bs = (long)CTOT * 3 * N, so = 0;
        dim3 gm5(N / 256, 3 * ((341 + OT - 1) / OT), B);
        k_matmul_plain<<<gm5, 256, 0, stream>>>(cat, W[4], bufU, N, CTOT, 341, bs, so);
        dim3 gmd(N / 256, 3, B);
        k_matmul_plain<<<gmd, 256, 0, stream>>>(cat, Dw[4], d5buf, N, CTOT, 1, bs, so);
        dim3 gs5(N / 256, 341, B);
        k_stats_plain<<<gs5, 256, 0, stream>>>(bufU, stats + 4 * 682, N, 341);
        k_final_plain<<<gs5, 256, 0, stream>>>(bufU, d5buf, stats + 4 * 682,
                                               G[4], Bt[4], (float*)d_out,
                                               N, 341, (float)((size_t)B * N));
    }
}

// Round 2
// 947.856 us; speedup vs baseline: 1.3849x; 1.3849x over previous
//
#include <hip/hip_runtime.h>
#include <math.h>

#define KNN 20
#define NS 0.2f
#define EPSV 1e-6f
#define QT 4
#define OT 8

// ---------------- transpose (B,N,3) -> (B,3,N) ----------------
__global__ void k_transpose(const float* __restrict__ x, float* __restrict__ xt,
                            int B, int N) {
    int i = blockIdx.x * blockDim.x + threadIdx.x;
    if (i >= B * N) return;
    int b = i / N, n = i % N;
    const float* src = x + (size_t)(b * N + n) * 3;
    float* dst = xt + (size_t)b * 3 * N + n;
    dst[0] = src[0];
    dst[(size_t)N] = src[1];
    dst[(size_t)2 * N] = src[2];
}

// ---------------- squared norms xx[b,n] = sum_d X[b,d,n]^2 ----------------
__global__ void k_sqnorm(const float* __restrict__ X, float* __restrict__ xx,
                         int B, int N, int D, long batchStride, long sliceOff) {
    int i = blockIdx.x * blockDim.x + threadIdx.x;
    if (i >= B * N) return;
    int b = i / N, n = i % N;
    const float* p = X + (size_t)b * batchStride + sliceOff + n;
    float s = 0.f;
    for (int d = 0; d < D; ++d) {
        float v = p[(size_t)d * N];
        s += v * v;
    }
    xx[i] = s;
}

// ---------------- knn: 4 waves/block, wave-local top-k (no barriers in selection) ----------------
__global__ void k_knn(const float* __restrict__ X, const float* __restrict__ xx,
                      int* __restrict__ idx, int N, int D,
                      long batchStride, long sliceOff) {
    int b = blockIdx.y;
    int q0 = blockIdx.x * QT;
    int tid = threadIdx.x;
    int lane = tid & 63;
    int wave = tid >> 6;

    __shared__ float qf[QT][128];     // D <= 126
    __shared__ float pd[QT][1024];    // N == 1024

    const float* Xb = X + (size_t)b * batchStride + sliceOff;

    for (int t = tid; t < QT * D; t += 256) {
        int q = t / D, d = t % D;
        qf[q][d] = Xb[(size_t)d * N + (q0 + q)];
    }
    __syncthreads();

    float acc[QT * 4];
#pragma unroll
    for (int t = 0; t < QT * 4; ++t) acc[t] = 0.f;

    for (int d = 0; d < D; ++d) {
        const float* row = Xb + (size_t)d * N;
        float x0 = row[tid], x1 = row[tid + 256], x2 = row[tid + 512], x3 = row[tid + 768];
#pragma unroll
        for (int q = 0; q < QT; ++q) {
            float qv = qf[q][d];
            acc[q * 4 + 0] += qv * x0;
            acc[q * 4 + 1] += qv * x1;
            acc[q * 4 + 2] += qv * x2;
            acc[q * 4 + 3] += qv * x3;
        }
    }

#pragma unroll
    for (int q = 0; q < QT; ++q) {
        float xn = xx[b * N + q0 + q];
#pragma unroll
        for (int c = 0; c < 4; ++c) {
            int m = tid + 256 * c;
            pd[q][m] = 2.f * acc[q * 4 + c] - xn - xx[b * N + m];
        }
    }
    __syncthreads();

    // wave `wave` selects top-KNN of pd[wave][0..1023]; lane holds 16 regs,
    // slot t => global index t*64+lane (conflict-free LDS reads).
    float v[16];
#pragma unroll
    for (int t = 0; t < 16; ++t) v[t] = pd[wave][t * 64 + lane];

    long outBase = ((long)b * N + q0 + wave) * KNN;
    for (int it = 0; it < KNN; ++it) {
        // local argmax (strict > keeps lowest t on ties; index = t*64+lane,
        // lower t == lower index for fixed lane)
        float bv = v[0];
        int bi = lane;
#pragma unroll
        for (int t = 1; t < 16; ++t) {
            if (v[t] > bv) { bv = v[t]; bi = t * 64 + lane; }
        }
        // 64-lane butterfly reduce, tie -> lower index; all lanes converge
#pragma unroll
        for (int off = 32; off >= 1; off >>= 1) {
            float ov = __shfl_xor(bv, off, 64);
            int oi = __shfl_xor(bi, off, 64);
            if (ov > bv || (ov == bv && oi < bi)) { bv = ov; bi = oi; }
        }
        if (lane == 0) idx[outBase + it] = bi;
        // invalidate winner (branch-free per-slot check, no dynamic reg index)
#pragma unroll
        for (int t = 0; t < 16; ++t) {
            if (bi == t * 64 + lane) v[t] = -INFINITY;
        }
    }
}

// ---------------- merged pair matmul: U=WA*x, V=(WB-WA)*x, same for Dw ----------------
__global__ void k_matmul_pair2(const float* __restrict__ X, const float* __restrict__ W,
                               const float* __restrict__ Dw,
                               float* __restrict__ U, float* __restrict__ V,
                               float* __restrict__ UD, float* __restrict__ VD,
                               int N, int C, int Cout, long batchStride, long sliceOff) {
    int j = blockIdx.y % 3;
    int ot = blockIdx.y / 3;
    int b = blockIdx.z;
    int o0 = ot * OT;
    int tid = threadIdx.x;
    int n = blockIdx.x * 256 + tid;

    __shared__ float wa[OT][64], wb[OT][64], da[OT][64], db[OT][64];   // C <= 42
    for (int t = tid; t < OT * C; t += 256) {
        int oo = t / C, c = t % C;
        int o = o0 + oo;
        float a = 0.f, bb = 0.f, xa = 0.f, xb = 0.f;
        if (o < Cout) {
            a = W[(size_t)o * 2 * C + c];
            bb = W[(size_t)o * 2 * C + C + c] - a;
            xa = Dw[(size_t)o * 2 * C + c];
            xb = Dw[(size_t)o * 2 * C + C + c] - xa;
        }
        wa[oo][c] = a; wb[oo][c] = bb;
        da[oo][c] = xa; db[oo][c] = xb;
    }
    __syncthreads();

    const float* Xp = X + (size_t)b * batchStride + sliceOff + (size_t)j * N + n;
    float au[OT], av[OT], cu[OT], cv[OT];
#pragma unroll
    for (int oo = 0; oo < OT; ++oo) { au[oo] = 0.f; av[oo] = 0.f; cu[oo] = 0.f; cv[oo] = 0.f; }

    for (int c = 0; c < C; ++c) {
        float xv = Xp[(size_t)c * 3 * N];
#pragma unroll
        for (int oo = 0; oo < OT; ++oo) {
            au[oo] += wa[oo][c] * xv;
            av[oo] += wb[oo][c] * xv;
            cu[oo] += da[oo][c] * xv;
            cv[oo] += db[oo][c] * xv;
        }
    }
#pragma unroll
    for (int oo = 0; oo < OT; ++oo) {
        int o = o0 + oo;
        if (o < Cout) {
            size_t off = (((size_t)b * Cout + o) * 3 + j) * N + n;
            U[off] = au[oo];
            V[off] = av[oo];
            UD[off] = cu[oo];
            VD[off] = cv[oo];
        }
    }
}

// ---------------- plain matmul (layer 5): U = W*x ----------------
__global__ void k_matmul_plain(const float* __restrict__ X, const float* __restrict__ W,
                               float* __restrict__ U,
                               int N, int Cin, int Cout, long batchStride, long sliceOff) {
    int j = blockIdx.y % 3;
    int ot = blockIdx.y / 3;
    int b = blockIdx.z;
    int o0 = ot * OT;
    int tid = threadIdx.x;
    int n = blockIdx.x * 256 + tid;

    __shared__ float wsm[OT][176];  // Cin <= 169
    for (int t = tid; t < OT * Cin; t += 256) {
        int oo = t / Cin, c = t % Cin;
        int o = o0 + oo;
        wsm[oo][c] = (o < Cout) ? W[(size_t)o * Cin + c] : 0.f;
    }
    __syncthreads();

    const float* Xp = X + (size_t)b * batchStride + sliceOff + (size_t)j * N + n;
    float au[OT];
#pragma unroll
    for (int oo = 0; oo < OT; ++oo) au[oo] = 0.f;

    for (int c = 0; c < Cin; ++c) {
        float xv = Xp[(size_t)c * 3 * N];
#pragma unroll
        for (int oo = 0; oo < OT; ++oo) au[oo] += wsm[oo][c] * xv;
    }
#pragma unroll
    for (int oo = 0; oo < OT; ++oo) {
        int o = o0 + oo;
        if (o < Cout) U[(((size_t)b * Cout + o) * 3 + j) * N + n] = au[oo];
    }
}

// ---------------- BN stats over edges: sums[2o]=Σ||p||, sums[2o+1]=Σ||p||² ----------------
__global__ void k_stats_edge(const float* __restrict__ U, const float* __restrict__ V,
                             const int* __restrict__ idx, float* __restrict__ sums,
                             int N, int Cout) {
    int b = blockIdx.z, o = blockIdx.y, tid = threadIdx.x;
    int n = blockIdx.x * 256 + tid;
    const float* Ub = U + (((size_t)b * Cout + o) * 3) * N;
    const float* Vb = V + (((size_t)b * Cout + o) * 3) * N;
    float v0 = Vb[n], v1 = Vb[(size_t)N + n], v2 = Vb[(size_t)2 * N + n];
    const int* ip = idx + ((size_t)b * N + n) * KNN;
    float s = 0.f, s2 = 0.f;
    for (int kk = 0; kk < KNN; ++kk) {
        int m = ip[kk];
        float p0 = Ub[m] + v0;
        float p1 = Ub[(size_t)N + m] + v1;
        float p2 = Ub[(size_t)2 * N + m] + v2;
        float nm = sqrtf(p0 * p0 + p1 * p1 + p2 * p2) + EPSV;
        s += nm;
        s2 += nm * nm;
    }
    __shared__ float r1[256], r2[256];
    r1[tid] = s; r2[tid] = s2;
    __syncthreads();
    for (int st = 128; st > 0; st >>= 1) {
        if (tid < st) { r1[tid] += r1[tid + st]; r2[tid] += r2[tid + st]; }
        __syncthreads();
    }
    if (tid == 0) {
        atomicAdd(&sums[2 * o], r1[0]);
        atomicAdd(&sums[2 * o + 1], r2[0]);
    }
}

// ---------------- BN + dir leaky + mean-pool over k -> out slice ----------------
__global__ void k_final_edge(const float* __restrict__ U, const float* __restrict__ V,
                             const float* __restrict__ UD, const float* __restrict__ VD,
                             const int* __restrict__ idx, const float* __restrict__ sums,
                             const float* __restrict__ gamma, const float* __restrict__ beta,
                             float* __restrict__ out,
                             int N, int Cout, int outCtot, int outCoff, float cnt) {
    int b = blockIdx.z, o = blockIdx.y, tid = threadIdx.x;
    int n = blockIdx.x * 256 + tid;
    float mu = sums[2 * o] / cnt;
    float var = sums[2 * o + 1] / cnt - mu * mu;
    float inv = rsqrtf(var + 1e-5f);
    float g = gamma[o], bt = beta[o];

    const float* Ub = U + (((size_t)b * Cout + o) * 3) * N;
    const float* Vb = V + (((size_t)b * Cout + o) * 3) * N;
    const float* UDb = UD + (((size_t)b * Cout + o) * 3) * N;
    const float* VDb = VD + (((size_t)b * Cout + o) * 3) * N;

    float v0 = Vb[n], v1 = Vb[(size_t)N + n], v2 = Vb[(size_t)2 * N + n];
    float w0 = VDb[n], w1 = VDb[(size_t)N + n], w2 = VDb[(size_t)2 * N + n];
    const int* ip = idx + ((size_t)b * N + n) * KNN;

    float a0 = 0.f, a1 = 0.f, a2 = 0.f;
    for (int kk = 0; kk < KNN; ++kk) {
        int m = ip[kk];
        float p0 = Ub[m] + v0;
        float p1 = Ub[(size_t)N + m] + v1;
        float p2 = Ub[(size_t)2 * N + m] + v2;
        float nm = sqrtf(p0 * p0 + p1 * p1 + p2 * p2) + EPSV;
        float nbn = (nm - mu) * inv * g + bt;
        float sc = nbn / nm;
        p0 *= sc; p1 *= sc; p2 *= sc;
        float d0 = UDb[m] + w0;
        float d1 = UDb[(size_t)N + m] + w1;
        float d2 = UDb[(size_t)2 * N + m] + w2;
        float dot = p0 * d0 + p1 * d1 + p2 * d2;
        if (dot >= 0.f) {
            a0 += p0; a1 += p1; a2 += p2;
        } else {
            float f = dot / (d0 * d0 + d1 * d1 + d2 * d2 + EPSV);
            a0 += NS * p0 + (1.f - NS) * (p0 - f * d0);
            a1 += NS * p1 + (1.f - NS) * (p1 - f * d1);
            a2 += NS * p2 + (1.f - NS) * (p2 - f * d2);
        }
    }
    const float invk = 1.f / (float)KNN;
    size_t ob = (((size_t)b * outCtot + outCoff + o) * 3) * N + n;
    out[ob] = a0 * invk;
    out[ob + (size_t)N] = a1 * invk;
    out[ob + (size_t)2 * N] = a2 * invk;
}

// ---------------- layer-5 stats (no k) ----------------
__global__ void k_stats_plain(const float* __restrict__ U, float* __restrict__ sums,
                              int N, int Cout) {
    int b = blockIdx.z, o = blockIdx.y, tid = threadIdx.x;
    int n = blockIdx.x * 256 + tid;
    const float* Ub = U + (((size_t)b * Cout + o) * 3) * N;
    float p0 = Ub[n], p1 = Ub[(size_t)N + n], p2 = Ub[(size_t)2 * N + n];
    float nm = sqrtf(p0 * p0 + p1 * p1 + p2 * p2) + EPSV;
    __shared__ float r1[256], r2[256];
    r1[tid] = nm; r2[tid] = nm * nm;
    __syncthreads();
    for (int st = 128; st > 0; st >>= 1) {
        if (tid < st) { r1[tid] += r1[tid + st]; r2[tid] += r2[tid + st]; }
        __syncthreads();
    }
    if (tid == 0) {
        atomicAdd(&sums[2 * o], r1[0]);
        atomicAdd(&sums[2 * o + 1], r2[0]);
    }
}

// ---------------- layer-5 final: BN + dir leaky (1 dir channel) -> d_out ----------------
__global__ void k_final_plain(const float* __restrict__ U, const float* __restrict__ Dv,
                              const float* __restrict__ sums,
                              const float* __restrict__ gamma, const float* __restrict__ beta,
                              float* __restrict__ out, int N, int Cout, float cnt) {
    int b = blockIdx.z, o = blockIdx.y, tid = threadIdx.x;
    int n = blockIdx.x * 256 + tid;
    float mu = sums[2 * o] / cnt;
    float var = sums[2 * o + 1] / cnt - mu * mu;
    float inv = rsqrtf(var + 1e-5f);
    float g = gamma[o], bt = beta[o];

    const float* Ub = U + (((size_t)b * Cout + o) * 3) * N;
    float p0 = Ub[n], p1 = Ub[(size_t)N + n], p2 = Ub[(size_t)2 * N + n];
    float nm = sqrtf(p0 * p0 + p1 * p1 + p2 * p2) + EPSV;
    float nbn = (nm - mu) * inv * g + bt;
    float sc = nbn / nm;
    p0 *= sc; p1 *= sc; p2 *= sc;

    float d0 = Dv[((size_t)b * 3 + 0) * N + n];
    float d1 = Dv[((size_t)b * 3 + 1) * N + n];
    float d2 = Dv[((size_t)b * 3 + 2) * N + n];
    float dot = p0 * d0 + p1 * d1 + p2 * d2;
    float o0, o1, o2;
    if (dot >= 0.f) {
        o0 = p0; o1 = p1; o2 = p2;
    } else {
        float f = dot / (d0 * d0 + d1 * d1 + d2 * d2 + EPSV);
        o0 = NS * p0 + (1.f - NS) * (p0 - f * d0);
        o1 = NS * p1 + (1.f - NS) * (p1 - f * d1);
        o2 = NS * p2 + (1.f - NS) * (p2 - f * d2);
    }
    size_t ob = (((size_t)b * Cout + o) * 3) * N + n;
    out[ob] = o0;
    out[ob + (size_t)N] = o1;
    out[ob + (size_t)2 * N] = o2;
}

extern "C" void kernel_launch(void* const* d_in, const int* in_sizes, int n_in,
                              void* d_out, int out_size, void* d_ws, size_t ws_size,
                              hipStream_t stream) {
    (void)in_sizes; (void)n_in; (void)out_size; (void)ws_size;
    const int B = 8, N = 1024, CTOT = 169;

    const float* x = (const float*)d_in[0];
    const float* W[5]; const float* Dw[5]; const float* G[5]; const float* Bt[5];
    for (int l = 0; l < 5; ++l) {
        W[l]  = (const float*)d_in[1 + 4 * l];
        Dw[l] = (const float*)d_in[2 + 4 * l];
        G[l]  = (const float*)d_in[3 + 4 * l];
        Bt[l] = (const float*)d_in[4 + 4 * l];
    }

    float* ws = (float*)d_ws;
    size_t off = 0;
    float* xt = ws + off;    off += (size_t)B * 3 * N;
    float* xx = ws + off;    off += (size_t)B * N;
    int* idx = (int*)(ws + off); off += (size_t)B * N * KNN;
    float* cat = ws + off;   off += (size_t)B * CTOT * 3 * N;
    float* bufU = ws + off;  off += (size_t)B * 341 * 3 * N;
    float* bufV = ws + off;  off += (size_t)B * 85 * 3 * N;
    float* bufUD = ws + off; off += (size_t)B * 85 * 3 * N;
    float* bufVD = ws + off; off += (size_t)B * 85 * 3 * N;
    float* d5buf = ws + off; off += (size_t)B * 3 * N;
    float* stats = ws + off; off += 5 * 682;

    hipMemsetAsync(stats, 0, 5 * 682 * sizeof(float), stream);

    k_transpose<<<(B * N + 255) / 256, 256, 0, stream>>>(x, xt, B, N);

    // layers 1-4: {C_in, C_out, inCoff (into cat; -1 => xt), outCoff}
    const int Cin_[4]  = {1, 21, 21, 42};
    const int Cout_[4] = {21, 21, 42, 85};
    const int inOff_[4] = {-1, 0, 21, 42};
    const int outOff_[4] = {0, 21, 42, 84};

    for (int l = 0; l < 4; ++l) {
        int C = Cin_[l], Co = Cout_[l];
        const float* Xin;
        long bs, so;
        if (inOff_[l] < 0) { Xin = xt; bs = (long)3 * N; so = 0; }
        else { Xin = cat; bs = (long)CTOT * 3 * N; so = (long)inOff_[l] * 3 * N; }
        int D = C * 3;

        k_sqnorm<<<(B * N + 255) / 256, 256, 0, stream>>>(Xin, xx, B, N, D, bs, so);

        dim3 gk(N / QT, B);
        k_knn<<<gk, 256, 0, stream>>>(Xin, xx, idx, N, D, bs, so);

        dim3 gm(N / 256, 3 * ((Co + OT - 1) / OT), B);
        k_matmul_pair2<<<gm, 256, 0, stream>>>(Xin, W[l], Dw[l], bufU, bufV, bufUD, bufVD,
                                               N, C, Co, bs, so);

        dim3 gs(N / 256, Co, B);
        k_stats_edge<<<gs, 256, 0, stream>>>(bufU, bufV, idx, stats + l * 682, N, Co);
        k_final_edge<<<gs, 256, 0, stream>>>(bufU, bufV, bufUD, bufVD, idx,
                                             stats + l * 682, G[l], Bt[l], cat,
                                             N, Co, CTOT, outOff_[l],
                                             (float)((size_t)B * N * KNN));
    }

    // layer 5 (no graph feature)
    {
        long bs = (long)CTOT * 3 * N, so = 0;
        dim3 gm5(N / 256, 3 * ((341 + OT - 1) / OT), B);
        k_matmul_plain<<<gm5, 256, 0, stream>>>(cat, W[4], bufU, N, CTOT, 341, bs, so);
        dim3 gmd(N / 256, 3, B);
        k_matmul_plain<<<gmd, 256, 0, stream>>>(cat, Dw[4], d5buf, N, CTOT, 1, bs, so);
        dim3 gs5(N / 256, 341, B);
        k_stats_plain<<<gs5, 256, 0, stream>>>(bufU, stats + 4 * 682, N, 341);
        k_final_plain<<<gs5, 256, 0, stream>>>(bufU, d5buf, stats + 4 * 682,
                                               G[4], Bt[4], (float*)d_out,
                                               N, 341, (float)((size_t)B * N));
    }
}